// Round 12
// baseline (86.730 us; speedup 1.0000x reference)
//
#include <hip/hip_runtime.h>
#include <math.h>

#define NTR 2048
#define MTE 4096
#define DIM 16
#define TT 4
#define NT 8192          // NTR * TT
#define KIT 16           // max preconditioned PIPECG iterations
#define NBLK 256         // persistent blocks (1 per CU, forced via LDS pad)
#define ROWS 8           // train rows per block
#define TOL2 4e-6f       // exit: gamma <= TOL2 * gamma0 (rel resid ~2e-3)

typedef unsigned long long u64;

// workspace layout (float offsets; u64 regions 8B-aligned)
#define OFF_M     0                       // m vector, 2 slots    2*NT floats
#define OFF_X     (OFF_M + 2*NT)          // x vector (1 slot)    NT floats
#define OFF_ST    (OFF_X + NT)            // sentinels: 2 slots x 2*NBLK u64
                                          // slot s, block b: [2b]=gamma, [2b+1]=delta

__device__ __forceinline__ u64 tagw(unsigned g, float v) {
    return ((u64)g << 32) | (u64)__float_as_uint(v);
}
__device__ __forceinline__ float payf(u64 w) { return __uint_as_float((unsigned)w); }
__device__ __forceinline__ unsigned tago(u64 w) { return (unsigned)(w >> 32); }
__device__ __forceinline__ u64 pk2(float lo, float hi) {
    return ((u64)__float_as_uint(hi) << 32) | (u64)__float_as_uint(lo);
}

// Persistent pipelined PCG (Ghysels-Vanroose), block-Jacobi M^-1 = I (x) C,
// C = (Kt+D)^-1 by Sherman-Morrison. One payload-sentinel exchange per
// iteration. Publish: {m slices, x slices, delta word} -> vmcnt(0) ->
// gamma word (same cache line as delta). ALL FOUR waves poll the sentinel
// set redundantly (xor-butterfly -> every lane holds gamma/delta; each wave
// does its own acquire), so no LDS hand-off and no bottom-of-loop barrier:
// waves 1-3 cannot write the next uSm until their own poll sees this
// block's gamma publish, which wave 0 issues only after consuming uSm.
// Regular (non-cooperative) launch; 1 block/CU forced by a dynamic-LDS pad.
__global__ __launch_bounds__(256, 1) void k_pcg(
    const float* __restrict__ tx,  const float* __restrict__ ty,
    const float* __restrict__ xte, const float* __restrict__ ls,
    const float* __restrict__ mc,
    const float* __restrict__ tf,  const float* __restrict__ tv,
    const float* __restrict__ tn,  const float* __restrict__ nz,
    float* __restrict__ mbuf, float* __restrict__ xg,
    u64* __restrict__ st,
    float* __restrict__ out)
{
    __shared__ float KxxS[ROWS][NTR];      // 64 KB
    __shared__ float ilsS[DIM];
    __shared__ float arowS[ROWS][DIM];
    __shared__ float anormS[ROWS];
    __shared__ float uSm[32];
    __shared__ float xSl[32], rSl[32], uSl[32], wSl[32];
    __shared__ float pSl[32], sSl[32], zSl[32], qSl[32], mSl[32];
    __shared__ float xrS[16][DIM];
    __shared__ float xnS[16];

    const int tid = threadIdx.x;
    const int b = blockIdx.x;
    const int wv = tid >> 6, lane = tid & 63;
    const int i0 = b * ROWS;
    const int sl = lane & 31;
    const int pbase = lane & ~3;

    const float f0=tf[0], f1=tf[1], f2=tf[2], f3=tf[3];
    const float K00=fmaf(f0,f0,tv[0]), K01=f0*f1, K02=f0*f2, K03=f0*f3;
    const float K11=fmaf(f1,f1,tv[1]), K12=f1*f2, K13=f1*f3;
    const float K22=fmaf(f2,f2,tv[2]), K23=f2*f3;
    const float K33=fmaf(f3,f3,tv[3]);
    const float dz = nz[0];
    const int   t  = lane & 3;
    const float dn_t = tn[t] + dz;
    const float mc0 = mc[0], mc1 = mc[1], mc2 = mc[2], mc3 = mc[3];
    // C = (Kt + D)^-1 via Sherman-Morrison: full matrix + per-lane row t
    const float g0v=tv[0]+tn[0]+dz, g1v=tv[1]+tn[1]+dz, g2v=tv[2]+tn[2]+dz, g3v=tv[3]+tn[3]+dz;
    const float c0=1.f/g0v, c1=1.f/g1v, c2=1.f/g2v, c3=1.f/g3v;
    const float up0=c0*f0, up1=c1*f1, up2=c2*f2, up3=c3*f3;
    const float rden = 1.f/(1.f + f0*up0 + f1*up1 + f2*up2 + f3*up3);
    const float C00=c0-up0*up0*rden, C01=-up0*up1*rden, C02=-up0*up2*rden, C03=-up0*up3*rden;
    const float C11=c1-up1*up1*rden, C12=-up1*up2*rden, C13=-up1*up3*rden;
    const float C22=c2-up2*up2*rden, C23=-up2*up3*rden;
    const float C33=c3-up3*up3*rden;
    const float upt = (t==0)?up0:(t==1)?up1:(t==2)?up2:up3;
    const float Ct0 = ((t==0)?c0:0.f) - upt*up0*rden;
    const float Ct1 = ((t==1)?c1:0.f) - upt*up1*rden;
    const float Ct2 = ((t==2)?c2:0.f) - upt*up2*rden;
    const float Ct3 = ((t==3)?c3:0.f) - upt*up3*rden;

    if (tid < DIM) ilsS[tid] = 1.0f / ls[tid];
    __syncthreads();
    float4 il0 = *reinterpret_cast<const float4*>(&ilsS[0]);
    float4 il1 = *reinterpret_cast<const float4*>(&ilsS[4]);
    float4 il2 = *reinterpret_cast<const float4*>(&ilsS[8]);
    float4 il3 = *reinterpret_cast<const float4*>(&ilsS[12]);
    if (tid < ROWS*DIM) {
        int p = tid >> 4, d = tid & 15;
        arowS[p][d] = tx[(i0+p)*DIM + d] * ilsS[d];
    }
    __syncthreads();
    if (tid < ROWS) {
        float s = 0.f;
        #pragma unroll
        for (int d = 0; d < DIM; ++d) s = fmaf(arowS[tid][d], arowS[tid][d], s);
        anormS[tid] = s;
    }
    __syncthreads();

    // ---- phase A (local, no exchange): own slices r0, u0 = C r0; gamma0 part
    float gpart = 0.f;
    if (wv == 0) {
        float rv = (lane < 32) ? (ty[i0*TT + lane] - ((t==0)?mc0:(t==1)?mc1:(t==2)?mc2:mc3)) : 0.f;
        float r0s = __shfl(rv, pbase+0), r1s = __shfl(rv, pbase+1);
        float r2s = __shfl(rv, pbase+2), r3s = __shfl(rv, pbase+3);
        float uv = Ct0*r0s + Ct1*r1s + Ct2*r2s + Ct3*r3s;
        if (lane < 32) {
            rSl[lane]=rv; uSl[lane]=uv;
            xSl[lane]=0.f; pSl[lane]=0.f; sSl[lane]=0.f; zSl[lane]=0.f; qSl[lane]=0.f;
        }
        float g = (lane < 32) ? rv*uv : 0.f;
        #pragma unroll
        for (int off = 32; off; off >>= 1) g += __shfl_down(g, off);
        gpart = g;                         // valid in lane 0
    }

    // ---- build own Kxx rows in LDS; a_j on the fly; block-rotated j start
    {
        const float4* tx4 = reinterpret_cast<const float4*>(tx);
        for (int ii = 0; ii < NTR/256; ++ii) {
            int j = tid + (((ii + b) & (NTR/256 - 1)) << 8);
            float4 A0 = tx4[j*4+0], A1 = tx4[j*4+1], A2 = tx4[j*4+2], A3 = tx4[j*4+3];
            A0.x*=il0.x; A0.y*=il0.y; A0.z*=il0.z; A0.w*=il0.w;
            A1.x*=il1.x; A1.y*=il1.y; A1.z*=il1.z; A1.w*=il1.w;
            A2.x*=il2.x; A2.y*=il2.y; A2.z*=il2.z; A2.w*=il2.w;
            A3.x*=il3.x; A3.y*=il3.y; A3.z*=il3.z; A3.w*=il3.w;
            float an;
            an = A0.x*A0.x;          an = fmaf(A0.y,A0.y,an);
            an = fmaf(A0.z,A0.z,an); an = fmaf(A0.w,A0.w,an);
            an = fmaf(A1.x,A1.x,an); an = fmaf(A1.y,A1.y,an);
            an = fmaf(A1.z,A1.z,an); an = fmaf(A1.w,A1.w,an);
            an = fmaf(A2.x,A2.x,an); an = fmaf(A2.y,A2.y,an);
            an = fmaf(A2.z,A2.z,an); an = fmaf(A2.w,A2.w,an);
            an = fmaf(A3.x,A3.x,an); an = fmaf(A3.y,A3.y,an);
            an = fmaf(A3.z,A3.z,an); an = fmaf(A3.w,A3.w,an);
            #pragma unroll
            for (int rr = 0; rr < ROWS; ++rr) {
                float dot;
                dot = arowS[rr][0]*A0.x;            dot = fmaf(arowS[rr][1], A0.y, dot);
                dot = fmaf(arowS[rr][2], A0.z, dot); dot = fmaf(arowS[rr][3], A0.w, dot);
                dot = fmaf(arowS[rr][4], A1.x, dot); dot = fmaf(arowS[rr][5], A1.y, dot);
                dot = fmaf(arowS[rr][6], A1.z, dot); dot = fmaf(arowS[rr][7], A1.w, dot);
                dot = fmaf(arowS[rr][8], A2.x, dot); dot = fmaf(arowS[rr][9], A2.y, dot);
                dot = fmaf(arowS[rr][10],A2.z, dot); dot = fmaf(arowS[rr][11],A2.w, dot);
                dot = fmaf(arowS[rr][12],A3.x, dot); dot = fmaf(arowS[rr][13],A3.y, dot);
                dot = fmaf(arowS[rr][14],A3.z, dot); dot = fmaf(arowS[rr][15],A3.w, dot);
                float d2 = anormS[rr] + an - 2.f*dot;
                KxxS[rr][j] = __expf(-0.5f * fmaxf(d2, 0.f));
            }
        }
    }
    __syncthreads();

    const int r0_ = 2*wv, r1_ = r0_ + 1;

    // butterfly, then lane0 applies (optionally C then) Kt per row -> uSm
    auto finrows = [&](float a00,float a01,float a02,float a03,
                       float a10,float a11,float a12,float a13, bool applyC) {
        #pragma unroll
        for (int off = 32; off; off >>= 1) {
            a00 += __shfl_down(a00,off); a01 += __shfl_down(a01,off);
            a02 += __shfl_down(a02,off); a03 += __shfl_down(a03,off);
            a10 += __shfl_down(a10,off); a11 += __shfl_down(a11,off);
            a12 += __shfl_down(a12,off); a13 += __shfl_down(a13,off);
        }
        if (lane == 0) {
            if (applyC) {
                float b0 = C00*a00 + C01*a01 + C02*a02 + C03*a03;
                float b1 = C01*a00 + C11*a01 + C12*a02 + C13*a03;
                float b2 = C02*a00 + C12*a01 + C22*a02 + C23*a03;
                float b3 = C03*a00 + C13*a01 + C23*a02 + C33*a03;
                a00=b0; a01=b1; a02=b2; a03=b3;
                b0 = C00*a10 + C01*a11 + C02*a12 + C03*a13;
                b1 = C01*a10 + C11*a11 + C12*a12 + C13*a13;
                b2 = C02*a10 + C12*a11 + C22*a12 + C23*a13;
                b3 = C03*a10 + C13*a11 + C23*a12 + C33*a13;
                a10=b0; a11=b1; a12=b2; a13=b3;
            }
            uSm[r0_*4+0] = K00*a00 + K01*a01 + K02*a02 + K03*a03;
            uSm[r0_*4+1] = K01*a00 + K11*a01 + K12*a02 + K13*a03;
            uSm[r0_*4+2] = K02*a00 + K12*a01 + K22*a02 + K23*a03;
            uSm[r0_*4+3] = K03*a00 + K13*a01 + K23*a02 + K33*a03;
            uSm[r1_*4+0] = K00*a10 + K01*a11 + K02*a12 + K03*a13;
            uSm[r1_*4+1] = K01*a10 + K11*a11 + K12*a12 + K13*a13;
            uSm[r1_*4+2] = K02*a10 + K12*a11 + K22*a12 + K23*a13;
            uSm[r1_*4+3] = K03*a10 + K13*a11 + K23*a12 + K33*a13;
        }
        __syncthreads();
    };

    // ---- init matvec: s_r = sum_j Kxx[r,j] (y_j - mc); u-rows = Kt C s_r ----
    {
        float a00=0,a01=0,a02=0,a03=0,a10=0,a11=0,a12=0,a13=0;
        const float4* ty4 = reinterpret_cast<const float4*>(ty);
        for (int jb = 0; jb < NTR/64; ++jb) {
            int j = jb*64 + lane;
            float4 yv = ty4[j];
            float rx = yv.x - mc0, ry = yv.y - mc1, rz = yv.z - mc2, rw = yv.w - mc3;
            float k0 = KxxS[r0_][j], k1 = KxxS[r1_][j];
            a00 = fmaf(k0,rx,a00); a01 = fmaf(k0,ry,a01);
            a02 = fmaf(k0,rz,a02); a03 = fmaf(k0,rw,a03);
            a10 = fmaf(k1,rx,a10); a11 = fmaf(k1,ry,a11);
            a12 = fmaf(k1,rz,a12); a13 = fmaf(k1,rw,a13);
        }
        finrows(a00,a01,a02,a03,a10,a11,a12,a13, true);
    }

    // ALL-WAVE poll: spin on gamma/delta pairs of `tag`; xor-butterfly so
    // every lane ends with the full fixed-order sums; per-wave acquire.
    float gam_r = 0.f, del_r = 0.f;
    auto scalred = [&](unsigned tag) {
        u64* ss = st + (tag & 1u)*(2*NBLK);
        u64 ga[4], da[4];
        for (;;) {
            bool ok = true;
            #pragma unroll
            for (int k2 = 0; k2 < 4; ++k2) {
                int bb = lane + 64*k2;
                ga[k2] = __hip_atomic_load(&ss[2*bb],   __ATOMIC_RELAXED, __HIP_MEMORY_SCOPE_AGENT);
                da[k2] = __hip_atomic_load(&ss[2*bb+1], __ATOMIC_RELAXED, __HIP_MEMORY_SCOPE_AGENT);
                ok = ok && (tago(ga[k2]) >= tag) && (tago(da[k2]) >= tag);
            }
            if (__all(ok)) break;
            __builtin_amdgcn_s_sleep(1);
        }
        float g  = payf(ga[0]) + payf(ga[1]) + payf(ga[2]) + payf(ga[3]);
        float dl = payf(da[0]) + payf(da[1]) + payf(da[2]) + payf(da[3]);
        #pragma unroll
        for (int off = 32; off; off >>= 1) { g += __shfl_xor(g,off); dl += __shfl_xor(dl,off); }
        gam_r = g; del_r = dl;             // identical in every lane
        (void)__hip_atomic_load(&ss[2*b], __ATOMIC_ACQUIRE, __HIP_MEMORY_SCOPE_AGENT);
    };

    // ---- event 1: w0 = A u0; m0 = C w0 -> m slot 1; x=0; {gamma0, delta0}.
    //      Waves 1-3 prep the tail's test rows in the shadow; then all poll.
    if (wv == 0) {
        float uv = uSl[sl];
        float wn = uSm[sl] + dn_t * uv;
        float w0s = __shfl(wn, pbase+0), w1s = __shfl(wn, pbase+1);
        float w2s = __shfl(wn, pbase+2), w3s = __shfl(wn, pbase+3);
        float mn = Ct0*w0s + Ct1*w1s + Ct2*w2s + Ct3*w3s;
        if (lane < 32) { wSl[lane]=wn; mSl[lane]=mn; }
        int b2 = (lane & 15) * 2;
        float mlo = __shfl(mn, b2), mhi = __shfl(mn, b2+1);
        if (lane < 16)
            __hip_atomic_store(reinterpret_cast<u64*>(mbuf + 1*NT + i0*TT) + lane,
                               pk2(mlo, mhi), __ATOMIC_RELAXED, __HIP_MEMORY_SCOPE_AGENT);
        else if (lane < 32)
            __hip_atomic_store(reinterpret_cast<u64*>(xg + i0*TT) + (lane-16),
                               pk2(0.f, 0.f), __ATOMIC_RELAXED, __HIP_MEMORY_SCOPE_AGENT);
        float dl = (lane < 32) ? wn*uv : 0.f;
        #pragma unroll
        for (int off = 32; off; off >>= 1) dl += __shfl_down(dl, off);
        u64* ss = st + 1u*(2*NBLK);
        if (lane == 0)
            __hip_atomic_store(&ss[2*b+1], tagw(1u, dl), __ATOMIC_RELAXED, __HIP_MEMORY_SCOPE_AGENT);
        asm volatile("s_waitcnt vmcnt(0)" ::: "memory");
        if (lane == 0)
            __hip_atomic_store(&ss[2*b], tagw(1u, gpart), __ATOMIC_RELAXED, __HIP_MEMORY_SCOPE_AGENT);
    } else {
        for (int e = tid - 64; e < 16*DIM; e += 192) {
            int row = e >> 4, d = e & 15;
            xrS[row][d] = xte[(b*16 + row)*DIM + d] * ilsS[d];
        }
    }
    scalred(1u);

    // ---- main loop: iteration it consumes event it+1 (gam_r/del_r + m slot
    //      (it+1)&1), publishes event it+2. No bottom-of-loop barrier: the
    //      sentinel gates waves 1-3's next uSm write behind wave 0's consume.
    float gamma_prev = 1.f, alpha_prev = 1.f, gamma0 = 0.f;
    float g1h = 1e30f, g2h = 1e30f;
    for (int it = 0; it < KIT; ++it) {
        float gam = gam_r, del = del_r;
        if (it == 0) gamma0 = gam;
        if (!(gam > TOL2 * gamma0)) break;                 // converged / NaN
        if (it >= 4 && gam > 0.25f * g2h) break;           // fp32 stagnation
        float beta, alph;
        if (it == 0) { beta = 0.f; alph = gam / del; }
        else {
            beta = gam / gamma_prev;
            float den = del - beta * gam / alpha_prev;
            if (!(fabsf(den) > 1e-37f)) break;
            alph = gam / den;
        }

        // matvec: raw Kxx sums over plain vectorized m reads; Kt applied after
        {
            const float4* m4 = reinterpret_cast<const float4*>(mbuf + ((it+1)&1)*NT);
            float a00=0,a01=0,a02=0,a03=0,a10=0,a11=0,a12=0,a13=0;
            #pragma unroll 4
            for (int jb = 0; jb < NTR/64; ++jb) {
                int j = jb*64 + lane;
                float4 v = m4[j];
                float k0 = KxxS[r0_][j], k1 = KxxS[r1_][j];
                a00 = fmaf(k0,v.x,a00); a01 = fmaf(k0,v.y,a01);
                a02 = fmaf(k0,v.z,a02); a03 = fmaf(k0,v.w,a03);
                a10 = fmaf(k1,v.x,a10); a11 = fmaf(k1,v.y,a11);
                a12 = fmaf(k1,v.z,a12); a13 = fmaf(k1,v.w,a13);
            }
            finrows(a00,a01,a02,a03,a10,a11,a12,a13, false);
        }

        if (wv == 0) {
            const unsigned e2 = (unsigned)(it + 2);
            float mv = mSl[sl];
            float nv = uSm[sl] + dn_t * mv;            // full A m
            float zv = fmaf(beta, zSl[sl], nv);
            float qv = fmaf(beta, qSl[sl], mv);
            float sv = fmaf(beta, sSl[sl], wSl[sl]);
            float pv = fmaf(beta, pSl[sl], uSl[sl]);
            float xv = fmaf( alph, pv, xSl[sl]);
            float rv = fmaf(-alph, sv, rSl[sl]);
            float uv = fmaf(-alph, qv, uSl[sl]);
            float wn = fmaf(-alph, zv, wSl[sl]);
            float w0s = __shfl(wn, pbase+0), w1s = __shfl(wn, pbase+1);
            float w2s = __shfl(wn, pbase+2), w3s = __shfl(wn, pbase+3);
            float mn = Ct0*w0s + Ct1*w1s + Ct2*w2s + Ct3*w3s;
            if (lane < 32) {
                zSl[lane]=zv; qSl[lane]=qv; sSl[lane]=sv; pSl[lane]=pv;
                xSl[lane]=xv; rSl[lane]=rv; uSl[lane]=uv; wSl[lane]=wn; mSl[lane]=mn;
            }
            int b2 = (lane & 15) * 2;
            float mlo = __shfl(mn, b2), mhi = __shfl(mn, b2+1);
            float xlo = __shfl(xv, b2), xhi = __shfl(xv, b2+1);
            if (lane < 16)
                __hip_atomic_store(reinterpret_cast<u64*>(mbuf + (e2&1u)*NT + i0*TT) + lane,
                                   pk2(mlo, mhi), __ATOMIC_RELAXED, __HIP_MEMORY_SCOPE_AGENT);
            else if (lane < 32)
                __hip_atomic_store(reinterpret_cast<u64*>(xg + i0*TT) + (lane-16),
                                   pk2(xlo, xhi), __ATOMIC_RELAXED, __HIP_MEMORY_SCOPE_AGENT);
            float g  = (lane < 32) ? rv*uv : 0.f;
            float dl = (lane < 32) ? wn*uv : 0.f;
            #pragma unroll
            for (int off = 32; off; off >>= 1) { g += __shfl_down(g,off); dl += __shfl_down(dl,off); }
            u64* ss = st + (e2&1u)*(2*NBLK);
            if (lane == 0)
                __hip_atomic_store(&ss[2*b+1], tagw(e2, dl), __ATOMIC_RELAXED, __HIP_MEMORY_SCOPE_AGENT);
            asm volatile("s_waitcnt vmcnt(0)" ::: "memory");
            if (lane == 0)
                __hip_atomic_store(&ss[2*b], tagw(e2, g),  __ATOMIC_RELAXED, __HIP_MEMORY_SCOPE_AGENT);
        }
        scalred((unsigned)(it + 2));       // all waves poll; own acquire each
        gamma_prev = gam; alpha_prev = alph;
        g2h = g1h; g1h = gam;
    }

    // ---- tail: x visible (each wave's final scalred gates it); xrS ready.
    __syncthreads();
    if (tid < 16) {
        float s = 0.f;
        #pragma unroll
        for (int d = 0; d < DIM; ++d) s = fmaf(xrS[tid][d], xrS[tid][d], s);
        xnS[tid] = s;
    }
    __syncthreads();

    float acc[4][4];
    #pragma unroll
    for (int i = 0; i < 4; ++i)
        #pragma unroll
        for (int tt = 0; tt < 4; ++tt) acc[i][tt] = 0.f;
    const float4* xg4 = reinterpret_cast<const float4*>(xg);
    const float4* tx4 = reinterpret_cast<const float4*>(tx);
    for (int jb = 0; jb < NTR/64; ++jb) {
        int j = (((jb + b) & (NTR/64 - 1)) << 6) + lane;   // block-rotated
        float4 A0 = tx4[j*4+0], A1 = tx4[j*4+1], A2 = tx4[j*4+2], A3 = tx4[j*4+3];
        A0.x*=il0.x; A0.y*=il0.y; A0.z*=il0.z; A0.w*=il0.w;
        A1.x*=il1.x; A1.y*=il1.y; A1.z*=il1.z; A1.w*=il1.w;
        A2.x*=il2.x; A2.y*=il2.y; A2.z*=il2.z; A2.w*=il2.w;
        A3.x*=il3.x; A3.y*=il3.y; A3.z*=il3.z; A3.w*=il3.w;
        float an;
        an = A0.x*A0.x;          an = fmaf(A0.y,A0.y,an);
        an = fmaf(A0.z,A0.z,an); an = fmaf(A0.w,A0.w,an);
        an = fmaf(A1.x,A1.x,an); an = fmaf(A1.y,A1.y,an);
        an = fmaf(A1.z,A1.z,an); an = fmaf(A1.w,A1.w,an);
        an = fmaf(A2.x,A2.x,an); an = fmaf(A2.y,A2.y,an);
        an = fmaf(A2.z,A2.z,an); an = fmaf(A2.w,A2.w,an);
        an = fmaf(A3.x,A3.x,an); an = fmaf(A3.y,A3.y,an);
        an = fmaf(A3.z,A3.z,an); an = fmaf(A3.w,A3.w,an);
        float4 xj = xg4[j];
        #pragma unroll
        for (int rr = 0; rr < 4; ++rr) {
            int row = 4*wv + rr;
            float dot;
            dot = xrS[row][0]*A0.x;             dot = fmaf(xrS[row][1], A0.y, dot);
            dot = fmaf(xrS[row][2], A0.z, dot);  dot = fmaf(xrS[row][3], A0.w, dot);
            dot = fmaf(xrS[row][4], A1.x, dot);  dot = fmaf(xrS[row][5], A1.y, dot);
            dot = fmaf(xrS[row][6], A1.z, dot);  dot = fmaf(xrS[row][7], A1.w, dot);
            dot = fmaf(xrS[row][8], A2.x, dot);  dot = fmaf(xrS[row][9], A2.y, dot);
            dot = fmaf(xrS[row][10],A2.z, dot);  dot = fmaf(xrS[row][11],A2.w, dot);
            dot = fmaf(xrS[row][12],A3.x, dot);  dot = fmaf(xrS[row][13],A3.y, dot);
            dot = fmaf(xrS[row][14],A3.z, dot);  dot = fmaf(xrS[row][15],A3.w, dot);
            float d2 = xnS[row] + an - 2.f*dot;
            float e = __expf(-0.5f * fmaxf(d2, 0.f));
            acc[rr][0] = fmaf(e, xj.x, acc[rr][0]);
            acc[rr][1] = fmaf(e, xj.y, acc[rr][1]);
            acc[rr][2] = fmaf(e, xj.z, acc[rr][2]);
            acc[rr][3] = fmaf(e, xj.w, acc[rr][3]);
        }
    }
    #pragma unroll
    for (int off = 32; off; off >>= 1)
        #pragma unroll
        for (int rr = 0; rr < 4; ++rr) {
            acc[rr][0] += __shfl_down(acc[rr][0], off);
            acc[rr][1] += __shfl_down(acc[rr][1], off);
            acc[rr][2] += __shfl_down(acc[rr][2], off);
            acc[rr][3] += __shfl_down(acc[rr][3], off);
        }
    if (lane == 0) {
        #pragma unroll
        for (int rr = 0; rr < 4; ++rr) {
            float s0 = acc[rr][0], s1 = acc[rr][1], s2 = acc[rr][2], s3 = acc[rr][3];
            float4 o;
            o.x = mc0 + K00*s0 + K01*s1 + K02*s2 + K03*s3;
            o.y = mc1 + K01*s0 + K11*s1 + K12*s2 + K13*s3;
            o.z = mc2 + K02*s0 + K12*s1 + K22*s2 + K23*s3;
            o.w = mc3 + K03*s0 + K13*s1 + K23*s2 + K33*s3;
            reinterpret_cast<float4*>(out)[b*16 + 4*wv + rr] = o;
        }
    }
}

extern "C" void kernel_launch(void* const* d_in, const int* in_sizes, int n_in,
                              void* d_out, int out_size, void* d_ws, size_t ws_size,
                              hipStream_t stream) {
    const float* x  = (const float*)d_in[0];
    const float* tx = (const float*)d_in[1];
    const float* ty = (const float*)d_in[2];
    const float* ls = (const float*)d_in[3];
    const float* mc = (const float*)d_in[4];
    const float* tf = (const float*)d_in[5];
    const float* tv = (const float*)d_in[6];
    const float* tn = (const float*)d_in[7];
    const float* nz = (const float*)d_in[8];

    float* ws    = (float*)d_ws;
    float* m     = ws + OFF_M;
    float* xv    = ws + OFF_X;
    u64*   stp   = (u64*)(ws + OFF_ST);
    float* outp  = (float*)d_out;

    // zero sentinel words (2 slots x 2*NBLK u64 = 8 KB); replay-safe
    hipMemsetAsync((void*)stp, 0, 4*NBLK*sizeof(u64), stream);

    // Regular launch; 16 KB dynamic-LDS pad forces 1 block/CU so all 256
    // blocks are co-resident (256 CUs) without cooperative-launch overhead.
    k_pcg<<<dim3(NBLK), dim3(256), 16384, stream>>>(
        tx, ty, x, ls, mc, tf, tv, tn, nz, m, xv, stp, outp);
}

// Round 13
// 58.582 us; speedup vs baseline: 1.4805x; 1.4805x over previous
//
#include <hip/hip_runtime.h>
#include <math.h>

#define NTR 2048
#define MTE 4096
#define DIM 16
#define TT 4
#define NT 8192          // NTR * TT
#define KIT 16           // max preconditioned PIPECG iterations
#define NBLK 256         // persistent blocks (1 per CU, forced via LDS pad)
#define ROWS 8           // train rows per block
#define TOL2 4e-6f       // exit: gamma <= TOL2 * gamma0 (rel resid ~2e-3)

typedef unsigned long long u64;

// workspace layout (float offsets; u64 regions 8B-aligned)
#define OFF_M     0                       // m vector, 2 slots    2*NT floats
#define OFF_X     (OFF_M + 2*NT)          // x vector (1 slot)    NT floats
#define OFF_ST    (OFF_X + NT)            // sentinels: 2 slots x 2*NBLK u64
                                          // slot s, block b: [2b]=gamma, [2b+1]=delta

__device__ __forceinline__ u64 tagw(unsigned g, float v) {
    return ((u64)g << 32) | (u64)__float_as_uint(v);
}
__device__ __forceinline__ float payf(u64 w) { return __uint_as_float((unsigned)w); }
__device__ __forceinline__ unsigned tago(u64 w) { return (unsigned)(w >> 32); }
__device__ __forceinline__ u64 pk2(float lo, float hi) {
    return ((u64)__float_as_uint(hi) << 32) | (u64)__float_as_uint(lo);
}

// Persistent pipelined PCG (Ghysels-Vanroose), block-Jacobi M^-1 = I (x) C,
// C = (Kt+D)^-1 by Sherman-Morrison. One payload-sentinel exchange per
// iteration. Publish: {m slices, x slices, delta word} -> vmcnt(0) ->
// gamma word (same cache line as delta). WAVE 0 ONLY polls the sentinel
// set (R12's all-wave poll quadrupled L3 contention and regressed); result
// handed to waves 1-3 via scal[] + __syncthreads. Regular (non-cooperative)
// launch; 1 block/CU forced by a dynamic-LDS pad.
__global__ __launch_bounds__(256, 1) void k_pcg(
    const float* __restrict__ tx,  const float* __restrict__ ty,
    const float* __restrict__ xte, const float* __restrict__ ls,
    const float* __restrict__ mc,
    const float* __restrict__ tf,  const float* __restrict__ tv,
    const float* __restrict__ tn,  const float* __restrict__ nz,
    float* __restrict__ mbuf, float* __restrict__ xg,
    u64* __restrict__ st,
    float* __restrict__ out)
{
    __shared__ float KxxS[ROWS][NTR];      // 64 KB
    __shared__ float ilsS[DIM];
    __shared__ float arowS[ROWS][DIM];
    __shared__ float anormS[ROWS];
    __shared__ float uSm[32];
    __shared__ float xSl[32], rSl[32], uSl[32], wSl[32];
    __shared__ float pSl[32], sSl[32], zSl[32], qSl[32], mSl[32];
    __shared__ float scal[2];
    __shared__ float xrS[16][DIM];
    __shared__ float xnS[16];

    const int tid = threadIdx.x;
    const int b = blockIdx.x;
    const int wv = tid >> 6, lane = tid & 63;
    const int i0 = b * ROWS;
    const int sl = lane & 31;
    const int pbase = lane & ~3;

    const float f0=tf[0], f1=tf[1], f2=tf[2], f3=tf[3];
    const float K00=fmaf(f0,f0,tv[0]), K01=f0*f1, K02=f0*f2, K03=f0*f3;
    const float K11=fmaf(f1,f1,tv[1]), K12=f1*f2, K13=f1*f3;
    const float K22=fmaf(f2,f2,tv[2]), K23=f2*f3;
    const float K33=fmaf(f3,f3,tv[3]);
    const float dz = nz[0];
    const int   t  = lane & 3;
    const float dn_t = tn[t] + dz;
    const float mc0 = mc[0], mc1 = mc[1], mc2 = mc[2], mc3 = mc[3];
    // C = (Kt + D)^-1 via Sherman-Morrison: full matrix + per-lane row t
    const float g0v=tv[0]+tn[0]+dz, g1v=tv[1]+tn[1]+dz, g2v=tv[2]+tn[2]+dz, g3v=tv[3]+tn[3]+dz;
    const float c0=1.f/g0v, c1=1.f/g1v, c2=1.f/g2v, c3=1.f/g3v;
    const float up0=c0*f0, up1=c1*f1, up2=c2*f2, up3=c3*f3;
    const float rden = 1.f/(1.f + f0*up0 + f1*up1 + f2*up2 + f3*up3);
    const float C00=c0-up0*up0*rden, C01=-up0*up1*rden, C02=-up0*up2*rden, C03=-up0*up3*rden;
    const float C11=c1-up1*up1*rden, C12=-up1*up2*rden, C13=-up1*up3*rden;
    const float C22=c2-up2*up2*rden, C23=-up2*up3*rden;
    const float C33=c3-up3*up3*rden;
    const float upt = (t==0)?up0:(t==1)?up1:(t==2)?up2:up3;
    const float Ct0 = ((t==0)?c0:0.f) - upt*up0*rden;
    const float Ct1 = ((t==1)?c1:0.f) - upt*up1*rden;
    const float Ct2 = ((t==2)?c2:0.f) - upt*up2*rden;
    const float Ct3 = ((t==3)?c3:0.f) - upt*up3*rden;

    if (tid < DIM) ilsS[tid] = 1.0f / ls[tid];
    __syncthreads();
    float4 il0 = *reinterpret_cast<const float4*>(&ilsS[0]);
    float4 il1 = *reinterpret_cast<const float4*>(&ilsS[4]);
    float4 il2 = *reinterpret_cast<const float4*>(&ilsS[8]);
    float4 il3 = *reinterpret_cast<const float4*>(&ilsS[12]);
    if (tid < ROWS*DIM) {
        int p = tid >> 4, d = tid & 15;
        arowS[p][d] = tx[(i0+p)*DIM + d] * ilsS[d];
    }
    __syncthreads();
    if (tid < ROWS) {
        float s = 0.f;
        #pragma unroll
        for (int d = 0; d < DIM; ++d) s = fmaf(arowS[tid][d], arowS[tid][d], s);
        anormS[tid] = s;
    }
    __syncthreads();

    // ---- phase A (local, no exchange): own slices r0, u0 = C r0; gamma0 part
    float gpart = 0.f;
    if (wv == 0) {
        float rv = (lane < 32) ? (ty[i0*TT + lane] - ((t==0)?mc0:(t==1)?mc1:(t==2)?mc2:mc3)) : 0.f;
        float r0s = __shfl(rv, pbase+0), r1s = __shfl(rv, pbase+1);
        float r2s = __shfl(rv, pbase+2), r3s = __shfl(rv, pbase+3);
        float uv = Ct0*r0s + Ct1*r1s + Ct2*r2s + Ct3*r3s;
        if (lane < 32) {
            rSl[lane]=rv; uSl[lane]=uv;
            xSl[lane]=0.f; pSl[lane]=0.f; sSl[lane]=0.f; zSl[lane]=0.f; qSl[lane]=0.f;
        }
        float g = (lane < 32) ? rv*uv : 0.f;
        #pragma unroll
        for (int off = 32; off; off >>= 1) g += __shfl_down(g, off);
        gpart = g;                         // valid in lane 0
    }

    // ---- build own Kxx rows in LDS; a_j on the fly; block-rotated j start
    {
        const float4* tx4 = reinterpret_cast<const float4*>(tx);
        for (int ii = 0; ii < NTR/256; ++ii) {
            int j = tid + (((ii + b) & (NTR/256 - 1)) << 8);
            float4 A0 = tx4[j*4+0], A1 = tx4[j*4+1], A2 = tx4[j*4+2], A3 = tx4[j*4+3];
            A0.x*=il0.x; A0.y*=il0.y; A0.z*=il0.z; A0.w*=il0.w;
            A1.x*=il1.x; A1.y*=il1.y; A1.z*=il1.z; A1.w*=il1.w;
            A2.x*=il2.x; A2.y*=il2.y; A2.z*=il2.z; A2.w*=il2.w;
            A3.x*=il3.x; A3.y*=il3.y; A3.z*=il3.z; A3.w*=il3.w;
            float an;
            an = A0.x*A0.x;          an = fmaf(A0.y,A0.y,an);
            an = fmaf(A0.z,A0.z,an); an = fmaf(A0.w,A0.w,an);
            an = fmaf(A1.x,A1.x,an); an = fmaf(A1.y,A1.y,an);
            an = fmaf(A1.z,A1.z,an); an = fmaf(A1.w,A1.w,an);
            an = fmaf(A2.x,A2.x,an); an = fmaf(A2.y,A2.y,an);
            an = fmaf(A2.z,A2.z,an); an = fmaf(A2.w,A2.w,an);
            an = fmaf(A3.x,A3.x,an); an = fmaf(A3.y,A3.y,an);
            an = fmaf(A3.z,A3.z,an); an = fmaf(A3.w,A3.w,an);
            #pragma unroll
            for (int rr = 0; rr < ROWS; ++rr) {
                float dot;
                dot = arowS[rr][0]*A0.x;            dot = fmaf(arowS[rr][1], A0.y, dot);
                dot = fmaf(arowS[rr][2], A0.z, dot); dot = fmaf(arowS[rr][3], A0.w, dot);
                dot = fmaf(arowS[rr][4], A1.x, dot); dot = fmaf(arowS[rr][5], A1.y, dot);
                dot = fmaf(arowS[rr][6], A1.z, dot); dot = fmaf(arowS[rr][7], A1.w, dot);
                dot = fmaf(arowS[rr][8], A2.x, dot); dot = fmaf(arowS[rr][9], A2.y, dot);
                dot = fmaf(arowS[rr][10],A2.z, dot); dot = fmaf(arowS[rr][11],A2.w, dot);
                dot = fmaf(arowS[rr][12],A3.x, dot); dot = fmaf(arowS[rr][13],A3.y, dot);
                dot = fmaf(arowS[rr][14],A3.z, dot); dot = fmaf(arowS[rr][15],A3.w, dot);
                float d2 = anormS[rr] + an - 2.f*dot;
                KxxS[rr][j] = __expf(-0.5f * fmaxf(d2, 0.f));
            }
        }
    }
    __syncthreads();

    const int r0_ = 2*wv, r1_ = r0_ + 1;

    // butterfly, then lane0 applies (optionally C then) Kt per row -> uSm
    auto finrows = [&](float a00,float a01,float a02,float a03,
                       float a10,float a11,float a12,float a13, bool applyC) {
        #pragma unroll
        for (int off = 32; off; off >>= 1) {
            a00 += __shfl_down(a00,off); a01 += __shfl_down(a01,off);
            a02 += __shfl_down(a02,off); a03 += __shfl_down(a03,off);
            a10 += __shfl_down(a10,off); a11 += __shfl_down(a11,off);
            a12 += __shfl_down(a12,off); a13 += __shfl_down(a13,off);
        }
        if (lane == 0) {
            if (applyC) {
                float b0 = C00*a00 + C01*a01 + C02*a02 + C03*a03;
                float b1 = C01*a00 + C11*a01 + C12*a02 + C13*a03;
                float b2 = C02*a00 + C12*a01 + C22*a02 + C23*a03;
                float b3 = C03*a00 + C13*a01 + C23*a02 + C33*a03;
                a00=b0; a01=b1; a02=b2; a03=b3;
                b0 = C00*a10 + C01*a11 + C02*a12 + C03*a13;
                b1 = C01*a10 + C11*a11 + C12*a12 + C13*a13;
                b2 = C02*a10 + C12*a11 + C22*a12 + C23*a13;
                b3 = C03*a10 + C13*a11 + C23*a12 + C33*a13;
                a10=b0; a11=b1; a12=b2; a13=b3;
            }
            uSm[r0_*4+0] = K00*a00 + K01*a01 + K02*a02 + K03*a03;
            uSm[r0_*4+1] = K01*a00 + K11*a01 + K12*a02 + K13*a03;
            uSm[r0_*4+2] = K02*a00 + K12*a01 + K22*a02 + K23*a03;
            uSm[r0_*4+3] = K03*a00 + K13*a01 + K23*a02 + K33*a03;
            uSm[r1_*4+0] = K00*a10 + K01*a11 + K02*a12 + K03*a13;
            uSm[r1_*4+1] = K01*a10 + K11*a11 + K12*a12 + K13*a13;
            uSm[r1_*4+2] = K02*a10 + K12*a11 + K22*a12 + K23*a13;
            uSm[r1_*4+3] = K03*a10 + K13*a11 + K23*a12 + K33*a13;
        }
        __syncthreads();
    };

    // ---- init matvec: s_r = sum_j Kxx[r,j] (y_j - mc); u-rows = Kt C s_r ----
    {
        float a00=0,a01=0,a02=0,a03=0,a10=0,a11=0,a12=0,a13=0;
        const float4* ty4 = reinterpret_cast<const float4*>(ty);
        for (int jb = 0; jb < NTR/64; ++jb) {
            int j = jb*64 + lane;
            float4 yv = ty4[j];
            float rx = yv.x - mc0, ry = yv.y - mc1, rz = yv.z - mc2, rw = yv.w - mc3;
            float k0 = KxxS[r0_][j], k1 = KxxS[r1_][j];
            a00 = fmaf(k0,rx,a00); a01 = fmaf(k0,ry,a01);
            a02 = fmaf(k0,rz,a02); a03 = fmaf(k0,rw,a03);
            a10 = fmaf(k1,rx,a10); a11 = fmaf(k1,ry,a11);
            a12 = fmaf(k1,rz,a12); a13 = fmaf(k1,rw,a13);
        }
        finrows(a00,a01,a02,a03,a10,a11,a12,a13, true);
    }

    // wave0-only: spin on the gamma/delta cache-line pair; gamma word (stored
    // post-drain) certifies m/x/delta visibility. Fixed-order sum, acquire.
    auto scalred = [&](unsigned tag) {
        u64* ss = st + (tag & 1u)*(2*NBLK);
        u64 ga[4], da[4];
        for (;;) {
            bool ok = true;
            #pragma unroll
            for (int k2 = 0; k2 < 4; ++k2) {
                int bb = lane + 64*k2;
                ga[k2] = __hip_atomic_load(&ss[2*bb],   __ATOMIC_RELAXED, __HIP_MEMORY_SCOPE_AGENT);
                da[k2] = __hip_atomic_load(&ss[2*bb+1], __ATOMIC_RELAXED, __HIP_MEMORY_SCOPE_AGENT);
                ok = ok && (tago(ga[k2]) >= tag) && (tago(da[k2]) >= tag);
            }
            if (__all(ok)) break;
            __builtin_amdgcn_s_sleep(1);
        }
        float g  = payf(ga[0]) + payf(ga[1]) + payf(ga[2]) + payf(ga[3]);
        float dl = payf(da[0]) + payf(da[1]) + payf(da[2]) + payf(da[3]);
        #pragma unroll
        for (int off = 32; off; off >>= 1) { g += __shfl_down(g,off); dl += __shfl_down(dl,off); }
        if (lane == 0) { scal[0] = g; scal[1] = dl; }
        (void)__hip_atomic_load(&ss[2*b], __ATOMIC_ACQUIRE, __HIP_MEMORY_SCOPE_AGENT);
    };

    // ---- event 1: w0 = A u0; m0 = C w0 -> m slot 1; x=0; {gamma0, delta0}.
    //      Waves 1-3 prep the tail's test rows in the shadow. ----
    if (wv == 0) {
        float uv = uSl[sl];
        float wn = uSm[sl] + dn_t * uv;
        float w0s = __shfl(wn, pbase+0), w1s = __shfl(wn, pbase+1);
        float w2s = __shfl(wn, pbase+2), w3s = __shfl(wn, pbase+3);
        float mn = Ct0*w0s + Ct1*w1s + Ct2*w2s + Ct3*w3s;
        if (lane < 32) { wSl[lane]=wn; mSl[lane]=mn; }
        int b2 = (lane & 15) * 2;
        float mlo = __shfl(mn, b2), mhi = __shfl(mn, b2+1);
        if (lane < 16)
            __hip_atomic_store(reinterpret_cast<u64*>(mbuf + 1*NT + i0*TT) + lane,
                               pk2(mlo, mhi), __ATOMIC_RELAXED, __HIP_MEMORY_SCOPE_AGENT);
        else if (lane < 32)
            __hip_atomic_store(reinterpret_cast<u64*>(xg + i0*TT) + (lane-16),
                               pk2(0.f, 0.f), __ATOMIC_RELAXED, __HIP_MEMORY_SCOPE_AGENT);
        float dl = (lane < 32) ? wn*uv : 0.f;
        #pragma unroll
        for (int off = 32; off; off >>= 1) dl += __shfl_down(dl, off);
        u64* ss = st + 1u*(2*NBLK);
        if (lane == 0)
            __hip_atomic_store(&ss[2*b+1], tagw(1u, dl), __ATOMIC_RELAXED, __HIP_MEMORY_SCOPE_AGENT);
        asm volatile("s_waitcnt vmcnt(0)" ::: "memory");
        if (lane == 0)
            __hip_atomic_store(&ss[2*b], tagw(1u, gpart), __ATOMIC_RELAXED, __HIP_MEMORY_SCOPE_AGENT);
        scalred(1u);
    } else {
        for (int e = tid - 64; e < 16*DIM; e += 192) {
            int row = e >> 4, d = e & 15;
            xrS[row][d] = xte[(b*16 + row)*DIM + d] * ilsS[d];
        }
    }
    __syncthreads();

    // ---- main loop: iteration it consumes event it+1 (scal + m slot (it+1)&1),
    //      publishes event it+2 (m slot (it+2)&1, x, delta, gamma) ----
    float gamma_prev = 1.f, alpha_prev = 1.f, gamma0 = 0.f;
    float g1h = 1e30f, g2h = 1e30f;
    for (int it = 0; it < KIT; ++it) {
        float gam = scal[0], del = scal[1];
        if (it == 0) gamma0 = gam;
        if (!(gam > TOL2 * gamma0)) break;                 // converged / NaN
        if (it >= 4 && gam > 0.25f * g2h) break;           // fp32 stagnation
        float beta, alph;
        if (it == 0) { beta = 0.f; alph = gam / del; }
        else {
            beta = gam / gamma_prev;
            float den = del - beta * gam / alpha_prev;
            if (!(fabsf(den) > 1e-37f)) break;
            alph = gam / den;
        }

        // matvec: raw Kxx sums over plain vectorized m reads; Kt applied after
        {
            const float4* m4 = reinterpret_cast<const float4*>(mbuf + ((it+1)&1)*NT);
            float a00=0,a01=0,a02=0,a03=0,a10=0,a11=0,a12=0,a13=0;
            #pragma unroll 4
            for (int jb = 0; jb < NTR/64; ++jb) {
                int j = jb*64 + lane;
                float4 v = m4[j];
                float k0 = KxxS[r0_][j], k1 = KxxS[r1_][j];
                a00 = fmaf(k0,v.x,a00); a01 = fmaf(k0,v.y,a01);
                a02 = fmaf(k0,v.z,a02); a03 = fmaf(k0,v.w,a03);
                a10 = fmaf(k1,v.x,a10); a11 = fmaf(k1,v.y,a11);
                a12 = fmaf(k1,v.z,a12); a13 = fmaf(k1,v.w,a13);
            }
            finrows(a00,a01,a02,a03,a10,a11,a12,a13, false);
        }

        if (wv == 0) {
            const unsigned e2 = (unsigned)(it + 2);
            float mv = mSl[sl];
            float nv = uSm[sl] + dn_t * mv;            // full A m
            float zv = fmaf(beta, zSl[sl], nv);
            float qv = fmaf(beta, qSl[sl], mv);
            float sv = fmaf(beta, sSl[sl], wSl[sl]);
            float pv = fmaf(beta, pSl[sl], uSl[sl]);
            float xv = fmaf( alph, pv, xSl[sl]);
            float rv = fmaf(-alph, sv, rSl[sl]);
            float uv = fmaf(-alph, qv, uSl[sl]);
            float wn = fmaf(-alph, zv, wSl[sl]);
            float w0s = __shfl(wn, pbase+0), w1s = __shfl(wn, pbase+1);
            float w2s = __shfl(wn, pbase+2), w3s = __shfl(wn, pbase+3);
            float mn = Ct0*w0s + Ct1*w1s + Ct2*w2s + Ct3*w3s;
            if (lane < 32) {
                zSl[lane]=zv; qSl[lane]=qv; sSl[lane]=sv; pSl[lane]=pv;
                xSl[lane]=xv; rSl[lane]=rv; uSl[lane]=uv; wSl[lane]=wn; mSl[lane]=mn;
            }
            int b2 = (lane & 15) * 2;
            float mlo = __shfl(mn, b2), mhi = __shfl(mn, b2+1);
            float xlo = __shfl(xv, b2), xhi = __shfl(xv, b2+1);
            if (lane < 16)
                __hip_atomic_store(reinterpret_cast<u64*>(mbuf + (e2&1u)*NT + i0*TT) + lane,
                                   pk2(mlo, mhi), __ATOMIC_RELAXED, __HIP_MEMORY_SCOPE_AGENT);
            else if (lane < 32)
                __hip_atomic_store(reinterpret_cast<u64*>(xg + i0*TT) + (lane-16),
                                   pk2(xlo, xhi), __ATOMIC_RELAXED, __HIP_MEMORY_SCOPE_AGENT);
            float g  = (lane < 32) ? rv*uv : 0.f;
            float dl = (lane < 32) ? wn*uv : 0.f;
            #pragma unroll
            for (int off = 32; off; off >>= 1) { g += __shfl_down(g,off); dl += __shfl_down(dl,off); }
            u64* ss = st + (e2&1u)*(2*NBLK);
            if (lane == 0)
                __hip_atomic_store(&ss[2*b+1], tagw(e2, dl), __ATOMIC_RELAXED, __HIP_MEMORY_SCOPE_AGENT);
            asm volatile("s_waitcnt vmcnt(0)" ::: "memory");
            if (lane == 0)
                __hip_atomic_store(&ss[2*b], tagw(e2, g),  __ATOMIC_RELAXED, __HIP_MEMORY_SCOPE_AGENT);
            scalred(e2);
        }
        gamma_prev = gam; alpha_prev = alph;
        g2h = g1h; g1h = gam;
        __syncthreads();
    }

    // ---- tail: x visible (gated by each block's final scalred); xrS ready.
    //      acc_t' = sum_j e_j x_{j,t'}; out = mc + Kt acc; a_j on the fly ----
    if (tid < 16) {
        float s = 0.f;
        #pragma unroll
        for (int d = 0; d < DIM; ++d) s = fmaf(xrS[tid][d], xrS[tid][d], s);
        xnS[tid] = s;
    }
    __syncthreads();

    float acc[4][4];
    #pragma unroll
    for (int i = 0; i < 4; ++i)
        #pragma unroll
        for (int tt = 0; tt < 4; ++tt) acc[i][tt] = 0.f;
    const float4* xg4 = reinterpret_cast<const float4*>(xg);
    const float4* tx4 = reinterpret_cast<const float4*>(tx);
    for (int jb = 0; jb < NTR/64; ++jb) {
        int j = (((jb + b) & (NTR/64 - 1)) << 6) + lane;   // block-rotated
        float4 A0 = tx4[j*4+0], A1 = tx4[j*4+1], A2 = tx4[j*4+2], A3 = tx4[j*4+3];
        A0.x*=il0.x; A0.y*=il0.y; A0.z*=il0.z; A0.w*=il0.w;
        A1.x*=il1.x; A1.y*=il1.y; A1.z*=il1.z; A1.w*=il1.w;
        A2.x*=il2.x; A2.y*=il2.y; A2.z*=il2.z; A2.w*=il2.w;
        A3.x*=il3.x; A3.y*=il3.y; A3.z*=il3.z; A3.w*=il3.w;
        float an;
        an = A0.x*A0.x;          an = fmaf(A0.y,A0.y,an);
        an = fmaf(A0.z,A0.z,an); an = fmaf(A0.w,A0.w,an);
        an = fmaf(A1.x,A1.x,an); an = fmaf(A1.y,A1.y,an);
        an = fmaf(A1.z,A1.z,an); an = fmaf(A1.w,A1.w,an);
        an = fmaf(A2.x,A2.x,an); an = fmaf(A2.y,A2.y,an);
        an = fmaf(A2.z,A2.z,an); an = fmaf(A2.w,A2.w,an);
        an = fmaf(A3.x,A3.x,an); an = fmaf(A3.y,A3.y,an);
        an = fmaf(A3.z,A3.z,an); an = fmaf(A3.w,A3.w,an);
        float4 xj = xg4[j];
        #pragma unroll
        for (int rr = 0; rr < 4; ++rr) {
            int row = 4*wv + rr;
            float dot;
            dot = xrS[row][0]*A0.x;             dot = fmaf(xrS[row][1], A0.y, dot);
            dot = fmaf(xrS[row][2], A0.z, dot);  dot = fmaf(xrS[row][3], A0.w, dot);
            dot = fmaf(xrS[row][4], A1.x, dot);  dot = fmaf(xrS[row][5], A1.y, dot);
            dot = fmaf(xrS[row][6], A1.z, dot);  dot = fmaf(xrS[row][7], A1.w, dot);
            dot = fmaf(xrS[row][8], A2.x, dot);  dot = fmaf(xrS[row][9], A2.y, dot);
            dot = fmaf(xrS[row][10],A2.z, dot);  dot = fmaf(xrS[row][11],A2.w, dot);
            dot = fmaf(xrS[row][12],A3.x, dot);  dot = fmaf(xrS[row][13],A3.y, dot);
            dot = fmaf(xrS[row][14],A3.z, dot);  dot = fmaf(xrS[row][15],A3.w, dot);
            float d2 = xnS[row] + an - 2.f*dot;
            float e = __expf(-0.5f * fmaxf(d2, 0.f));
            acc[rr][0] = fmaf(e, xj.x, acc[rr][0]);
            acc[rr][1] = fmaf(e, xj.y, acc[rr][1]);
            acc[rr][2] = fmaf(e, xj.z, acc[rr][2]);
            acc[rr][3] = fmaf(e, xj.w, acc[rr][3]);
        }
    }
    #pragma unroll
    for (int off = 32; off; off >>= 1)
        #pragma unroll
        for (int rr = 0; rr < 4; ++rr) {
            acc[rr][0] += __shfl_down(acc[rr][0], off);
            acc[rr][1] += __shfl_down(acc[rr][1], off);
            acc[rr][2] += __shfl_down(acc[rr][2], off);
            acc[rr][3] += __shfl_down(acc[rr][3], off);
        }
    if (lane == 0) {
        #pragma unroll
        for (int rr = 0; rr < 4; ++rr) {
            float s0 = acc[rr][0], s1 = acc[rr][1], s2 = acc[rr][2], s3 = acc[rr][3];
            float4 o;
            o.x = mc0 + K00*s0 + K01*s1 + K02*s2 + K03*s3;
            o.y = mc1 + K01*s0 + K11*s1 + K12*s2 + K13*s3;
            o.z = mc2 + K02*s0 + K12*s1 + K22*s2 + K23*s3;
            o.w = mc3 + K03*s0 + K13*s1 + K23*s2 + K33*s3;
            reinterpret_cast<float4*>(out)[b*16 + 4*wv + rr] = o;
        }
    }
}

extern "C" void kernel_launch(void* const* d_in, const int* in_sizes, int n_in,
                              void* d_out, int out_size, void* d_ws, size_t ws_size,
                              hipStream_t stream) {
    const float* x  = (const float*)d_in[0];
    const float* tx = (const float*)d_in[1];
    const float* ty = (const float*)d_in[2];
    const float* ls = (const float*)d_in[3];
    const float* mc = (const float*)d_in[4];
    const float* tf = (const float*)d_in[5];
    const float* tv = (const float*)d_in[6];
    const float* tn = (const float*)d_in[7];
    const float* nz = (const float*)d_in[8];

    float* ws    = (float*)d_ws;
    float* m     = ws + OFF_M;
    float* xv    = ws + OFF_X;
    u64*   stp   = (u64*)(ws + OFF_ST);
    float* outp  = (float*)d_out;

    // zero sentinel words (2 slots x 2*NBLK u64 = 8 KB); replay-safe
    hipMemsetAsync((void*)stp, 0, 4*NBLK*sizeof(u64), stream);

    // Regular launch; 16 KB dynamic-LDS pad forces 1 block/CU so all 256
    // blocks are co-resident (256 CUs) without cooperative-launch overhead.
    k_pcg<<<dim3(NBLK), dim3(256), 16384, stream>>>(
        tx, ty, x, ls, mc, tf, tv, tn, nz, m, xv, stp, outp);
}